// Round 1
// baseline (103.672 us; speedup 1.0000x reference)
//
#include <hip/hip_runtime.h>

#define BATCH   8
#define NPTS    8192
#define THREADS 256
#define QPT     4                      // queries per thread
#define QBLK    (THREADS * QPT)        // 1024 queries per block
#define NQB     (NPTS / QBLK)          // 8 query-blocks per (batch,dir)
#define TSPLIT  8                      // target-dimension split
#define TSLICE  (NPTS / TSPLIT)        // 1024 targets per block
#define TILE    256                    // LDS tile of targets
#define NQ_TOTAL (BATCH * 2 * NPTS)    // 131072 total queries

// Stage 1: each block computes, for 1024 query points, the min of
// (||b||^2 - 2 a.b) over a 1024-target slice, then stores min + ||a||^2.
__global__ __launch_bounds__(THREADS) void chamfer_stage1(
    const float* __restrict__ A,   // [B, N, 3] "input"
    const float* __restrict__ Bp,  // [B, M, 3] "output"
    float* __restrict__ partial)   // [TSPLIT][NQ_TOTAL]
{
    __shared__ float4 tile[TILE];

    const int bid = blockIdx.x;
    const int ts  = bid & (TSPLIT - 1);
    const int qb  = (bid >> 3) & (NQB - 1);
    const int bd  = bid >> 6;          // 0..15  (batch*2 + dir)
    const int b   = bd >> 1;
    const int dir = bd & 1;

    const float* Q = (dir == 0) ? (A  + (size_t)b * NPTS * 3)
                                : (Bp + (size_t)b * NPTS * 3);
    const float* T = (dir == 0) ? (Bp + (size_t)b * NPTS * 3)
                                : (A  + (size_t)b * NPTS * 3);

    const int tid = threadIdx.x;

    float ax[QPT], ay[QPT], az[QPT], aa[QPT], mn[QPT];
#pragma unroll
    for (int k = 0; k < QPT; ++k) {
        const int q = qb * QBLK + k * THREADS + tid;
        ax[k] = Q[q * 3 + 0];
        ay[k] = Q[q * 3 + 1];
        az[k] = Q[q * 3 + 2];
        aa[k] = ax[k] * ax[k] + ay[k] * ay[k] + az[k] * az[k];
        mn[k] = 3.4e38f;
    }

    const int tbase = ts * TSLICE;
    for (int t0 = 0; t0 < TSLICE; t0 += TILE) {
        const int j = tbase + t0 + tid;
        const float bx = T[j * 3 + 0];
        const float by = T[j * 3 + 1];
        const float bz = T[j * 3 + 2];
        tile[tid] = make_float4(bx, by, bz, bx * bx + by * by + bz * bz);
        __syncthreads();

#pragma unroll 4
        for (int jj = 0; jj < TILE; ++jj) {
            const float4 bv = tile[jj];
#pragma unroll
            for (int k = 0; k < QPT; ++k) {
                float t = ax[k] * bv.x;
                t = fmaf(ay[k], bv.y, t);
                t = fmaf(az[k], bv.z, t);
                const float cand = fmaf(-2.0f, t, bv.w);   // ||b||^2 - 2 a.b
                mn[k] = fminf(mn[k], cand);
            }
        }
        __syncthreads();
    }

#pragma unroll
    for (int k = 0; k < QPT; ++k) {
        const int q = qb * QBLK + k * THREADS + tid;
        const int qglobal = bd * NPTS + q;
        partial[(size_t)ts * NQ_TOTAL + qglobal] = mn[k] + aa[k];
    }
}

__device__ inline float wave_reduce_sum(float v) {
#pragma unroll
    for (int off = 32; off; off >>= 1) v += __shfl_down(v, off, 64);
    return v;
}

// Stage 2: combine TSPLIT partial mins per query, block-sum 256 queries.
__global__ __launch_bounds__(THREADS) void chamfer_stage2(
    const float* __restrict__ partial, float* __restrict__ blocksum)
{
    const int qglobal = blockIdx.x * THREADS + threadIdx.x;
    float m = 3.4e38f;
#pragma unroll
    for (int ts = 0; ts < TSPLIT; ++ts)
        m = fminf(m, partial[(size_t)ts * NQ_TOTAL + qglobal]);

    __shared__ float wsum[THREADS / 64];
    const float s = wave_reduce_sum(m);
    if ((threadIdx.x & 63) == 0) wsum[threadIdx.x >> 6] = s;
    __syncthreads();
    if (threadIdx.x == 0) {
        float t = 0.f;
#pragma unroll
        for (int w = 0; w < THREADS / 64; ++w) t += wsum[w];
        blocksum[blockIdx.x] = t;
    }
}

// Stage 3: deterministic final reduction of 512 block sums.
__global__ __launch_bounds__(THREADS) void chamfer_stage3(
    const float* __restrict__ blocksum, float* __restrict__ out)
{
    // 512 values, 256 threads: 2 each
    float v = blocksum[threadIdx.x] + blocksum[threadIdx.x + THREADS];
    __shared__ float wsum[THREADS / 64];
    const float s = wave_reduce_sum(v);
    if ((threadIdx.x & 63) == 0) wsum[threadIdx.x >> 6] = s;
    __syncthreads();
    if (threadIdx.x == 0) {
        float t = 0.f;
#pragma unroll
        for (int w = 0; w < THREADS / 64; ++w) t += wsum[w];
        out[0] = t;
    }
}

extern "C" void kernel_launch(void* const* d_in, const int* in_sizes, int n_in,
                              void* d_out, int out_size, void* d_ws, size_t ws_size,
                              hipStream_t stream) {
    const float* A  = (const float*)d_in[0];   // "input"  [8,8192,3]
    const float* Bp = (const float*)d_in[1];   // "output" [8,8192,3]
    float* out = (float*)d_out;

    float* partial  = (float*)d_ws;                          // TSPLIT*NQ_TOTAL floats = 4 MB
    float* blocksum = partial + (size_t)TSPLIT * NQ_TOTAL;   // 512 floats

    const int nblocks1 = BATCH * 2 * NQB * TSPLIT;           // 1024
    chamfer_stage1<<<nblocks1, THREADS, 0, stream>>>(A, Bp, partial);

    const int nblocks2 = NQ_TOTAL / THREADS;                 // 512
    chamfer_stage2<<<nblocks2, THREADS, 0, stream>>>(partial, blocksum);

    chamfer_stage3<<<1, THREADS, 0, stream>>>(blocksum, out);
}

// Round 2
// 95.117 us; speedup vs baseline: 1.0899x; 1.0899x over previous
//
#include <hip/hip_runtime.h>

#define BATCH   8
#define NPTS    8192
#define THREADS 256
#define QPT     2                      // queries per thread
#define QBLK    (THREADS * QPT)        // 512 queries per block
#define NQB     (NPTS / QBLK)          // 16 query-blocks per (batch,dir)
#define TSPLIT  8                      // target-dimension split
#define TSLICE  (NPTS / TSPLIT)        // 1024 targets per block
#define TILE    256                    // LDS tile of targets
#define NQ_TOTAL (BATCH * 2 * NPTS)    // 131072 total queries

// Stage 1: each block computes, for 512 query points, the min of
// (||b||^2 - 2 a.b) over a 1024-target slice, then stores min + ||a||^2.
// Query coords are pre-scaled by -2 so the candidate is a 3-fma chain
// seeded with ||b||^2; two targets per min update -> v_min3_f32.
__global__ __launch_bounds__(THREADS) void chamfer_stage1(
    const float* __restrict__ A,   // [B, N, 3] "input"
    const float* __restrict__ Bp,  // [B, M, 3] "output"
    float* __restrict__ partial)   // [TSPLIT][NQ_TOTAL]
{
    __shared__ float4 tile[TILE];

    const int bid = blockIdx.x;
    const int ts  = bid & (TSPLIT - 1);          // 3 bits
    const int qb  = (bid >> 3) & (NQB - 1);      // 4 bits
    const int bd  = bid >> 7;                    // 0..15  (batch*2 + dir)
    const int b   = bd >> 1;
    const int dir = bd & 1;

    const float* Q = (dir == 0) ? (A  + (size_t)b * NPTS * 3)
                                : (Bp + (size_t)b * NPTS * 3);
    const float* T = (dir == 0) ? (Bp + (size_t)b * NPTS * 3)
                                : (A  + (size_t)b * NPTS * 3);

    const int tid = threadIdx.x;

    float ax2[QPT], ay2[QPT], az2[QPT], aa[QPT], mn[QPT];
#pragma unroll
    for (int k = 0; k < QPT; ++k) {
        const int q = qb * QBLK + k * THREADS + tid;
        const float x = Q[q * 3 + 0];
        const float y = Q[q * 3 + 1];
        const float z = Q[q * 3 + 2];
        aa[k]  = x * x + y * y + z * z;
        ax2[k] = -2.0f * x;
        ay2[k] = -2.0f * y;
        az2[k] = -2.0f * z;
        mn[k]  = 3.4e38f;
    }

    const int tbase = ts * TSLICE;
    for (int t0 = 0; t0 < TSLICE; t0 += TILE) {
        const int j = tbase + t0 + tid;
        const float bx = T[j * 3 + 0];
        const float by = T[j * 3 + 1];
        const float bz = T[j * 3 + 2];
        tile[tid] = make_float4(bx, by, bz, bx * bx + by * by + bz * bz);
        __syncthreads();

#pragma unroll 4
        for (int jj = 0; jj < TILE; jj += 2) {
            const float4 b0 = tile[jj];
            const float4 b1 = tile[jj + 1];
#pragma unroll
            for (int k = 0; k < QPT; ++k) {
                const float c0 = fmaf(az2[k], b0.z,
                                 fmaf(ay2[k], b0.y,
                                 fmaf(ax2[k], b0.x, b0.w)));
                const float c1 = fmaf(az2[k], b1.z,
                                 fmaf(ay2[k], b1.y,
                                 fmaf(ax2[k], b1.x, b1.w)));
                mn[k] = fminf(fminf(c0, c1), mn[k]);   // -> v_min3_f32
            }
        }
        __syncthreads();
    }

#pragma unroll
    for (int k = 0; k < QPT; ++k) {
        const int q = qb * QBLK + k * THREADS + tid;
        const int qglobal = bd * NPTS + q;
        partial[(size_t)ts * NQ_TOTAL + qglobal] = mn[k] + aa[k];
    }
}

__device__ inline float wave_reduce_sum(float v) {
#pragma unroll
    for (int off = 32; off; off >>= 1) v += __shfl_down(v, off, 64);
    return v;
}

// Stage 2: combine TSPLIT partial mins per query, block-sum 256 queries.
__global__ __launch_bounds__(THREADS) void chamfer_stage2(
    const float* __restrict__ partial, float* __restrict__ blocksum)
{
    const int qglobal = blockIdx.x * THREADS + threadIdx.x;
    float m = 3.4e38f;
#pragma unroll
    for (int ts = 0; ts < TSPLIT; ++ts)
        m = fminf(m, partial[(size_t)ts * NQ_TOTAL + qglobal]);

    __shared__ float wsum[THREADS / 64];
    const float s = wave_reduce_sum(m);
    if ((threadIdx.x & 63) == 0) wsum[threadIdx.x >> 6] = s;
    __syncthreads();
    if (threadIdx.x == 0) {
        float t = 0.f;
#pragma unroll
        for (int w = 0; w < THREADS / 64; ++w) t += wsum[w];
        blocksum[blockIdx.x] = t;
    }
}

// Stage 3: deterministic final reduction of 512 block sums.
__global__ __launch_bounds__(THREADS) void chamfer_stage3(
    const float* __restrict__ blocksum, float* __restrict__ out)
{
    float v = blocksum[threadIdx.x] + blocksum[threadIdx.x + THREADS];
    __shared__ float wsum[THREADS / 64];
    const float s = wave_reduce_sum(v);
    if ((threadIdx.x & 63) == 0) wsum[threadIdx.x >> 6] = s;
    __syncthreads();
    if (threadIdx.x == 0) {
        float t = 0.f;
#pragma unroll
        for (int w = 0; w < THREADS / 64; ++w) t += wsum[w];
        out[0] = t;
    }
}

extern "C" void kernel_launch(void* const* d_in, const int* in_sizes, int n_in,
                              void* d_out, int out_size, void* d_ws, size_t ws_size,
                              hipStream_t stream) {
    const float* A  = (const float*)d_in[0];   // "input"  [8,8192,3]
    const float* Bp = (const float*)d_in[1];   // "output" [8,8192,3]
    float* out = (float*)d_out;

    float* partial  = (float*)d_ws;                          // TSPLIT*NQ_TOTAL floats = 4 MB
    float* blocksum = partial + (size_t)TSPLIT * NQ_TOTAL;   // 512 floats

    const int nblocks1 = BATCH * 2 * NQB * TSPLIT;           // 2048
    chamfer_stage1<<<nblocks1, THREADS, 0, stream>>>(A, Bp, partial);

    const int nblocks2 = NQ_TOTAL / THREADS;                 // 512
    chamfer_stage2<<<nblocks2, THREADS, 0, stream>>>(partial, blocksum);

    chamfer_stage3<<<1, THREADS, 0, stream>>>(blocksum, out);
}

// Round 3
// 87.088 us; speedup vs baseline: 1.1904x; 1.0922x over previous
//
#include <hip/hip_runtime.h>

typedef float f32x2 __attribute__((ext_vector_type(2)));
typedef float f32x4 __attribute__((ext_vector_type(4)));

#define BATCH   8
#define NPTS    8192
#define THREADS 256
#define QPT     4                      // queries per thread
#define QBLK    (THREADS * QPT)        // 1024 queries per block
#define NQB     (NPTS / QBLK)          // 8 query-blocks per (batch,dir)
#define TSPLIT  8                      // target-dimension split
#define TSLICE  (NPTS / TSPLIT)        // 1024 targets per block
#define TILE    512                    // LDS tile of targets (SoA planes)
#define NQ_TOTAL (BATCH * 2 * NPTS)    // 131072 total queries

__device__ __forceinline__ f32x2 pk_fma(f32x2 a, f32x2 b, f32x2 c) {
    f32x2 d;
    asm("v_pk_fma_f32 %0, %1, %2, %3" : "=v"(d) : "v"(a), "v"(b), "v"(c));
    return d;
}
__device__ __forceinline__ float min3f(float a, float b, float c) {
    float d;
    asm("v_min3_f32 %0, %1, %2, %3" : "=v"(d) : "v"(a), "v"(b), "v"(c));
    return d;
}

// Stage 1: for 1024 query points, min of (||b||^2 - 2 a.b) over a
// 1024-target slice. Targets staged SoA in LDS; candidates computed
// two-at-a-time with v_pk_fma_f32, reduced with v_min3_f32.
__global__ __launch_bounds__(THREADS) void chamfer_stage1(
    const float* __restrict__ A,   // [B, N, 3] "input"
    const float* __restrict__ Bp,  // [B, M, 3] "output"
    float* __restrict__ partial)   // [TSPLIT][NQ_TOTAL]
{
    __shared__ __align__(16) float tx[TILE];
    __shared__ __align__(16) float ty[TILE];
    __shared__ __align__(16) float tz[TILE];
    __shared__ __align__(16) float tw[TILE];

    const int bid = blockIdx.x;
    const int ts  = bid & (TSPLIT - 1);          // 3 bits
    const int qb  = (bid >> 3) & (NQB - 1);      // 3 bits
    const int bd  = bid >> 6;                    // 0..15  (batch*2 + dir)
    const int b   = bd >> 1;
    const int dir = bd & 1;

    const float* Q = (dir == 0) ? (A  + (size_t)b * NPTS * 3)
                                : (Bp + (size_t)b * NPTS * 3);
    const float* T = (dir == 0) ? (Bp + (size_t)b * NPTS * 3)
                                : (A  + (size_t)b * NPTS * 3);

    const int tid = threadIdx.x;

    f32x2 qx[QPT], qy[QPT], qz[QPT];
    float aa[QPT], mn[QPT];
#pragma unroll
    for (int k = 0; k < QPT; ++k) {
        const int q = qb * QBLK + k * THREADS + tid;
        const float x = Q[q * 3 + 0];
        const float y = Q[q * 3 + 1];
        const float z = Q[q * 3 + 2];
        aa[k] = x * x + y * y + z * z;
        const float x2 = -2.0f * x, y2 = -2.0f * y, z2 = -2.0f * z;
        qx[k] = (f32x2){x2, x2};
        qy[k] = (f32x2){y2, y2};
        qz[k] = (f32x2){z2, z2};
        mn[k] = 3.4e38f;
    }

    const int tbase = ts * TSLICE;
    for (int t0 = 0; t0 < TSLICE; t0 += TILE) {
#pragma unroll
        for (int u = 0; u < TILE / THREADS; ++u) {
            const int t = u * THREADS + tid;
            const int j = tbase + t0 + t;
            const float x = T[j * 3 + 0];
            const float y = T[j * 3 + 1];
            const float z = T[j * 3 + 2];
            tx[t] = x; ty[t] = y; tz[t] = z;
            tw[t] = fmaf(z, z, fmaf(y, y, x * x));
        }
        __syncthreads();

#pragma unroll 2
        for (int jj = 0; jj < TILE; jj += 4) {
            const f32x4 bx = *(const f32x4*)&tx[jj];   // uniform-addr broadcast
            const f32x4 by = *(const f32x4*)&ty[jj];
            const f32x4 bz = *(const f32x4*)&tz[jj];
            const f32x4 bw = *(const f32x4*)&tw[jj];
            const f32x2 bx01 = __builtin_shufflevector(bx, bx, 0, 1);
            const f32x2 bx23 = __builtin_shufflevector(bx, bx, 2, 3);
            const f32x2 by01 = __builtin_shufflevector(by, by, 0, 1);
            const f32x2 by23 = __builtin_shufflevector(by, by, 2, 3);
            const f32x2 bz01 = __builtin_shufflevector(bz, bz, 0, 1);
            const f32x2 bz23 = __builtin_shufflevector(bz, bz, 2, 3);
            const f32x2 bw01 = __builtin_shufflevector(bw, bw, 0, 1);
            const f32x2 bw23 = __builtin_shufflevector(bw, bw, 2, 3);
#pragma unroll
            for (int k = 0; k < QPT; ++k) {
                f32x2 c01 = pk_fma(qx[k], bx01, bw01);
                c01 = pk_fma(qy[k], by01, c01);
                c01 = pk_fma(qz[k], bz01, c01);
                f32x2 c23 = pk_fma(qx[k], bx23, bw23);
                c23 = pk_fma(qy[k], by23, c23);
                c23 = pk_fma(qz[k], bz23, c23);
                mn[k] = min3f(c01.x, c01.y, mn[k]);
                mn[k] = min3f(c23.x, c23.y, mn[k]);
            }
        }
        __syncthreads();
    }

#pragma unroll
    for (int k = 0; k < QPT; ++k) {
        const int q = qb * QBLK + k * THREADS + tid;
        const int qglobal = bd * NPTS + q;
        partial[(size_t)ts * NQ_TOTAL + qglobal] = mn[k] + aa[k];
    }
}

__device__ inline float wave_reduce_sum(float v) {
#pragma unroll
    for (int off = 32; off; off >>= 1) v += __shfl_down(v, off, 64);
    return v;
}

// Stage 2: combine TSPLIT partial mins per query, block-sum 256 queries.
__global__ __launch_bounds__(THREADS) void chamfer_stage2(
    const float* __restrict__ partial, float* __restrict__ blocksum)
{
    const int qglobal = blockIdx.x * THREADS + threadIdx.x;
    float m = 3.4e38f;
#pragma unroll
    for (int ts = 0; ts < TSPLIT; ++ts)
        m = fminf(m, partial[(size_t)ts * NQ_TOTAL + qglobal]);

    __shared__ float wsum[THREADS / 64];
    const float s = wave_reduce_sum(m);
    if ((threadIdx.x & 63) == 0) wsum[threadIdx.x >> 6] = s;
    __syncthreads();
    if (threadIdx.x == 0) {
        float t = 0.f;
#pragma unroll
        for (int w = 0; w < THREADS / 64; ++w) t += wsum[w];
        blocksum[blockIdx.x] = t;
    }
}

// Stage 3: deterministic final reduction of 512 block sums.
__global__ __launch_bounds__(THREADS) void chamfer_stage3(
    const float* __restrict__ blocksum, float* __restrict__ out)
{
    float v = blocksum[threadIdx.x] + blocksum[threadIdx.x + THREADS];
    __shared__ float wsum[THREADS / 64];
    const float s = wave_reduce_sum(v);
    if ((threadIdx.x & 63) == 0) wsum[threadIdx.x >> 6] = s;
    __syncthreads();
    if (threadIdx.x == 0) {
        float t = 0.f;
#pragma unroll
        for (int w = 0; w < THREADS / 64; ++w) t += wsum[w];
        out[0] = t;
    }
}

extern "C" void kernel_launch(void* const* d_in, const int* in_sizes, int n_in,
                              void* d_out, int out_size, void* d_ws, size_t ws_size,
                              hipStream_t stream) {
    const float* A  = (const float*)d_in[0];   // "input"  [8,8192,3]
    const float* Bp = (const float*)d_in[1];   // "output" [8,8192,3]
    float* out = (float*)d_out;

    float* partial  = (float*)d_ws;                          // TSPLIT*NQ_TOTAL floats = 4 MB
    float* blocksum = partial + (size_t)TSPLIT * NQ_TOTAL;   // 512 floats

    const int nblocks1 = BATCH * 2 * NQB * TSPLIT;           // 1024
    chamfer_stage1<<<nblocks1, THREADS, 0, stream>>>(A, Bp, partial);

    const int nblocks2 = NQ_TOTAL / THREADS;                 // 512
    chamfer_stage2<<<nblocks2, THREADS, 0, stream>>>(partial, blocksum);

    chamfer_stage3<<<1, THREADS, 0, stream>>>(blocksum, out);
}